// Round 7
// baseline (408.536 us; speedup 1.0000x reference)
//
#include <hip/hip_runtime.h>
#include <cfloat>

// ClDiceLoss (B=2, C=1, 192^3) fp32 — LDS-staged register-streaming skeletonize.
//
// Round-14. Rounds 8/10/11/13 all plateau at 77-83us: compiler sinks the
// plane loads to use (VGPR=60 across all), every step starts with a full
// exposed VMEM latency on 15 scattered dwordx3, and more waves just deepen
// the queue (r13: 2x grid -> dur flat). Fix: staging via
// __builtin_amdgcn_global_load_lds (side-effecting -> UNSINKABLE) in the
// T3/T4 counted-vmcnt + raw-barrier pattern:
//   - block stages an 8-row contiguous slab of plane z+2 into a ring-4 LDS
//     buffer: 8 x (size=12, 64 lanes x 12B = one 768B row), 2 ops/wave/step
//     (vs 20 sinkable row-loads; intra-block halo re-read eliminated).
//   - per step: [weight(last)][stage z+2][s_waitcnt vmcnt(6|8)][s_barrier]
//     [ds_read 5 rows of plane z -> regs][M/P/out as before].
//     vmcnt(6)=keep stage(s)+stage(s-1)+newest store/weight in flight =
//     2-step prefetch across barriers. Uniform op protocol (dummy store /
//     dummy weight on non-emit steps + 1 prologue dummy store) makes the
//     count exact at EVERY step (verified by induction on the op window).
//   - plane regs: ring-4 of 5-row sets, read once per plane (SC turn),
//     reused as SM1/SM2; all indices static via 4-phase unroll.
// Race discipline: slot overwritten at step s was last read at step s-2,
// whose ds_reads are lgkm-drained before barrier(s-1) -> one barrier
// separates read-retire from overwrite. Prologue ends with lgkmcnt(0) +
// barrier before the loop's first overwrite of slot 0.
// Kept: bijective XCD swizzle, CZ=24 (1536 blocks), dwordx3 stores,
// separable 3x3 max, y/z boundary handling identical to round-13.

constexpr int D = 192, H = 192, W = 192, B = 2;
constexpr int HW = H * W;
constexpr int VOL = D * HW;
constexpr int CZ = 24;               // z-chunk (divides D)
constexpr int NCH = D / CZ;          // 8
constexpr int WPB = 4;               // waves (rows) per block
constexpr int NGY = H / WPB;         // 48
constexpr int STEPS = 32;            // padded to mult of 4; emit s in [3,CZ+2]
constexpr int NPART = B * NCH * H;   // 3072 per chain
constexpr int MAXWG = NGY * NCH * 2 * B;  // 1536

struct F3 { float x, y, z; };

typedef __attribute__((address_space(3))) float lds_f;
typedef __attribute__((address_space(1))) const float glb_f;

__device__ __forceinline__ float min3f(float a, float b, float c) {
  return fminf(fminf(a, b), c);
}
__device__ __forceinline__ float max3f(float a, float b, float c) {
  return fmaxf(fmaxf(a, b), c);
}

__global__ __launch_bounds__(256, 4) void skel_iter(
    const float* __restrict__ srcA, float* __restrict__ dstA,
    const float* __restrict__ othA, double* __restrict__ partA,
    const float* __restrict__ srcB, float* __restrict__ dstB,
    const float* __restrict__ othB, double* __restrict__ partB,
    float* __restrict__ dump, int last) {
  __shared__ float slab[4][8][192];   // ring-4 of 8-row plane slabs (24.5 KB)

  const int tid = threadIdx.x, lane = tid & 63, wv = tid >> 6;
  const int bid0 = blockIdx.x + gridDim.x * (blockIdx.y + gridDim.y * blockIdx.z);
  const int nwg = gridDim.x * gridDim.y * gridDim.z;
  const int wid = (bid0 & 7) * (nwg >> 3) + (bid0 >> 3);   // XCD swizzle
  const int gyg = wid % NGY;
  const int combo = wid / NGY;
  const int chunk = combo % NCH;
  const int bz = combo / NCH;
  const int b = bz % B;
  const int chain = bz / B;

  const int gy0 = gyg * WPB;
  const int gy = gy0 + wv;

  const float* __restrict__ vs = (chain ? srcB : srcA) + (size_t)b * VOL;
  float* __restrict__ vd = (chain ? dstB : dstA) + (size_t)b * VOL;
  const float* __restrict__ vo = (chain ? othB : othA) + (size_t)b * VOL;
  double* __restrict__ part = chain ? partB : partA;

  const int z0 = chunk * CZ;
  const int c0 = 3 * lane;
  const int wrow = gy * W + c0;
  float* __restrict__ dmp = dump + (size_t)bid0 * 192 + c0;

  // slab-row read offsets (floats), y-clamped to duplicated edge rows
  int roff[5];
  #pragma unroll
  for (int r = 0; r < 5; ++r) {
    const int i = min(max(gy - 2 + r, 0), H - 1) - (gy0 - 2);
    roff[r] = i * 192 + c0;
  }
  const bool ytop = (gy == 0), ybot = (gy == H - 1);
  const bool l0 = (lane == 0), l63 = (lane == 63);

  // staging rows owned by this wave: slab rows wv and wv+4
  const int g0 = min(max(gy0 - 2 + wv, 0), H - 1);
  const int g1 = min(max(gy0 + 2 + wv, 0), H - 1);

  auto stage = [&](int plane, int slot) {
    const int zc = min(max(plane, 0), D - 1);
    const float* s0 = vs + (size_t)zc * HW + (size_t)g0 * W + c0;
    const float* s1 = vs + (size_t)zc * HW + (size_t)g1 * W + c0;
    __builtin_amdgcn_global_load_lds((glb_f*)s0, (lds_f*)&slab[slot][wv][0], 12, 0, 0);
    __builtin_amdgcn_global_load_lds((glb_f*)s1, (lds_f*)&slab[slot][wv + 4][0], 12, 0, 0);
  };

  float xa[4][5][3];                  // plane reg ring (slot s%4 = plane z)
  float Mprev[3] = {0, 0, 0}, h1[3] = {0, 0, 0}, h2[3] = {0, 0, 0};
  float sp = 0.0f, ss = 0.0f;

  // ---- prologue: slabs z0-3..z0 -> slots 0..3; seed reg sets ----
  stage(z0 - 3, 0);
  stage(z0 - 2, 1);
  stage(z0 - 1, 2);
  asm volatile("s_waitcnt vmcnt(0)" ::: "memory");
  __builtin_amdgcn_s_barrier();
  __builtin_amdgcn_sched_barrier(0);
  {
    const float* sp0 = &slab[0][0][0];
    const float* sp1 = &slab[1][0][0];
    #pragma unroll
    for (int r = 1; r <= 3; ++r) {    // OLD init: plane z0-3, rows gy-1..gy+1
      xa[2][r][0] = sp0[roff[r]]; xa[2][r][1] = sp0[roff[r] + 1]; xa[2][r][2] = sp0[roff[r] + 2];
    }
    #pragma unroll
    for (int r = 0; r < 5; ++r) {     // MID init: plane z0-2, 5 rows
      xa[3][r][0] = sp1[roff[r]]; xa[3][r][1] = sp1[roff[r] + 1]; xa[3][r][2] = sp1[roff[r] + 2];
    }
  }
  xa[2][0][0] = xa[2][0][1] = xa[2][0][2] = 0.0f;   // never read; keep defined
  xa[2][4][0] = xa[2][4][1] = xa[2][4][2] = 0.0f;
  stage(z0, 3);                       // virtual step -1: stage
  *(F3*)dmp = {0.0f, 0.0f, 0.0f};     // virtual step -1: store (protocol)
  asm volatile("s_waitcnt lgkmcnt(0)" ::: "memory");
  __builtin_amdgcn_s_barrier();
  __builtin_amdgcn_sched_barrier(0);

  #pragma unroll 1
  for (int s4 = 0; s4 < STEPS; s4 += 4) {
    #pragma unroll
    for (int p = 0; p < 4; ++p) {
      const int s = s4 + p;
      const int z = z0 - 1 + s;
      const int zo = z - 2;
      const bool emit = (s >= 3) && (s <= CZ + 2);
      const int NEW = p, OLD = (p + 2) & 3, MID = (p + 3) & 3;
      const int RS = (p + 2) & 3;     // lds slot of plane z

      // 1. weight (last only; dummy on non-emit keeps op count uniform)
      float w0 = 0.f, w1 = 0.f, w2 = 0.f;
      if (last) {
        const F3 wv3 = *(const F3*)(emit ? (vo + (size_t)zo * HW + wrow) : (vo + wrow));
        w0 = wv3.x; w1 = wv3.y; w2 = wv3.z;
      }
      // 2. stage plane z+2 -> slot p (unsinkable)
      stage(z + 2, p);
      // 3. counted wait (slab z complete; stage(s), stage(s-1) stay in
      //    flight) + raw barrier
      if (last) asm volatile("s_waitcnt vmcnt(8)" ::: "memory");
      else      asm volatile("s_waitcnt vmcnt(6)" ::: "memory");
      __builtin_amdgcn_s_barrier();
      __builtin_amdgcn_sched_barrier(0);

      // 4. read plane z's 5 rows -> NEW reg set
      {
        const float* rp = &slab[RS][0][0];
        #pragma unroll
        for (int r = 0; r < 5; ++r) {
          xa[NEW][r][0] = rp[roff[r]];
          xa[NEW][r][1] = rp[roff[r] + 1];
          xa[NEW][r][2] = rp[roff[r] + 2];
        }
      }

      // 5. M(z-1): 7-pt cross min (center plane = MID)
      float xl[3], xr[3];
      #pragma unroll
      for (int r = 0; r < 3; ++r) {
        xl[r] = __shfl_up(xa[MID][r + 1][2], 1, 64);
        xr[r] = __shfl_down(xa[MID][r + 1][0], 1, 64);
        if (l0) xl[r] = FLT_MAX;
        if (l63) xr[r] = FLT_MAX;
      }
      float Mc[3][3];
      #pragma unroll
      for (int r = 0; r < 3; ++r) {
        #pragma unroll
        for (int c = 0; c < 3; ++c) {
          const float le = (c == 0) ? xl[r] : xa[MID][r + 1][c - 1];
          const float ri = (c == 2) ? xr[r] : xa[MID][r + 1][c + 1];
          float v = min3f(xa[MID][r + 1][c], le, ri);
          v = min3f(v, xa[MID][r][c], xa[MID][r + 2][c]);       // y+-1
          v = min3f(v, xa[OLD][r + 1][c], xa[NEW][r + 1][c]);   // z+-1
          Mc[r][c] = v;
        }
      }
      if (ytop) { Mc[0][0] = Mc[0][1] = Mc[0][2] = -FLT_MAX; }
      if (ybot) { Mc[2][0] = Mc[2][1] = Mc[2][2] = -FLT_MAX; }

      // 6. hxy(z-1): separable 3x3 max
      float rm[3];
      #pragma unroll
      for (int c = 0; c < 3; ++c) rm[c] = max3f(Mc[0][c], Mc[1][c], Mc[2][c]);
      float ml = __shfl_up(rm[2], 1, 64);
      float mr = __shfl_down(rm[0], 1, 64);
      if (l0) ml = -FLT_MAX;
      if (l63) mr = -FLT_MAX;
      float h0c[3];
      h0c[0] = max3f(ml, rm[0], rm[1]);
      h0c[1] = max3f(rm[0], rm[1], rm[2]);
      h0c[2] = max3f(rm[1], rm[2], mr);

      // 7. out(z-2) = relu(x - relu(P - M)); uniform 1 store/step
      {
        const bool zlo = (zo > 0), zhi = (zo < D - 1);
        float o[3];
        #pragma unroll
        for (int c = 0; c < 3; ++c) {
          float P = h1[c];
          if (zlo) P = fmaxf(P, h2[c]);
          if (zhi) P = fmaxf(P, h0c[c]);
          const float contour = fmaxf(P - Mprev[c], 0.0f);
          o[c] = fmaxf(xa[OLD][2][c] - contour, 0.0f);
        }
        float* dst = (!last && emit) ? (vd + (size_t)zo * HW + wrow) : dmp;
        *(F3*)dst = {o[0], o[1], o[2]};
        if (last && emit) {
          sp += o[0] * w0 + o[1] * w1 + o[2] * w2;
          ss += o[0] + o[1] + o[2];
        }
      }
      #pragma unroll
      for (int c = 0; c < 3; ++c) {
        h2[c] = h1[c]; h1[c] = h0c[c]; Mprev[c] = Mc[1][c];
      }
    }
  }

  if (last) {
    #pragma unroll
    for (int off = 32; off > 0; off >>= 1) {
      sp += __shfl_down(sp, off, 64);
      ss += __shfl_down(ss, off, 64);
    }
    if (lane == 0) {
      const int lin = (b * NCH + chunk) * H + gy;
      part[2 * lin] = (double)sp;
      part[2 * lin + 1] = (double)ss;
    }
  }
}

__global__ void finalize_kernel(const double* __restrict__ pa,
                                const double* __restrict__ pb,
                                float* __restrict__ out, int npart) {
  __shared__ double red[4][4];
  double s[4] = {0, 0, 0, 0};
  for (int i = threadIdx.x; i < npart; i += 256) {
    s[0] += pa[2 * i];
    s[1] += pa[2 * i + 1];
    s[2] += pb[2 * i];
    s[3] += pb[2 * i + 1];
  }
  #pragma unroll
  for (int off = 32; off > 0; off >>= 1)
    #pragma unroll
    for (int j = 0; j < 4; ++j) s[j] += __shfl_down(s[j], off, 64);
  const int wave = threadIdx.x >> 6, lane = threadIdx.x & 63;
  if (lane == 0)
    for (int j = 0; j < 4; ++j) red[j][wave] = s[j];
  __syncthreads();
  if (threadIdx.x == 0) {
    double t[4];
    for (int j = 0; j < 4; ++j)
      t[j] = red[j][0] + red[j][1] + red[j][2] + red[j][3];
    const double recall = (t[0] + 1e-12) / (t[1] + 1e-12);
    const double accv = (t[2] + 1e-12) / (t[3] + 1e-12);
    const double cldice = 2.0 * recall * accv / (recall + accv);
    out[0] = (float)(1.0 - cldice);
  }
}

extern "C" void kernel_launch(void* const* d_in, const int* in_sizes, int n_in,
                              void* d_out, int out_size, void* d_ws, size_t ws_size,
                              hipStream_t stream) {
  const float* pred = (const float*)d_in[0];
  const float* target = (const float*)d_in[1];
  float* out = (float*)d_out;
  const size_t NT = (size_t)VOL * B;
  const size_t DUMPSZ = (size_t)MAXWG * 192;

  const dim3 blk(256, 1, 1);
  const size_t need_merged =
      4 * NT * sizeof(float) + 4 * NPART * sizeof(double) + DUMPSZ * sizeof(float);

  if (ws_size >= need_merged) {
    float* a0 = (float*)d_ws;
    float* a1 = a0 + NT;
    float* c0 = a1 + NT;
    float* c1 = c0 + NT;
    double* pA = (double*)(c1 + NT);
    double* pB = pA + 2 * NPART;
    float* dump = (float*)(pB + 2 * NPART);
    const dim3 grd(NGY, NCH, 2 * B);   // 1536 blocks
    skel_iter<<<grd, blk, 0, stream>>>(target, a0, pred, pA, pred, c0, target, pB, dump, 0);
    skel_iter<<<grd, blk, 0, stream>>>(a0, a1, pred, pA, c0, c1, target, pB, dump, 0);
    skel_iter<<<grd, blk, 0, stream>>>(a1, a0, pred, pA, c1, c0, target, pB, dump, 0);
    skel_iter<<<grd, blk, 0, stream>>>(a0, a1, pred, pA, c0, c1, target, pB, dump, 0);
    skel_iter<<<grd, blk, 0, stream>>>(a1, a0, pred, pA, c1, c0, target, pB, dump, 1);
    finalize_kernel<<<1, 256, 0, stream>>>(pA, pB, out, NPART);
  } else {
    float* b0 = (float*)d_ws;
    float* b1 = b0 + NT;
    double* pA = (double*)(b1 + NT);
    double* pB = pA + 2 * NPART;
    float* dump = (float*)(pB + 2 * NPART);
    const dim3 grd(NGY, NCH, B);       // chain 0 only, 768 blocks
    skel_iter<<<grd, blk, 0, stream>>>(target, b0, pred, pA, nullptr, nullptr, nullptr, nullptr, dump, 0);
    skel_iter<<<grd, blk, 0, stream>>>(b0, b1, pred, pA, nullptr, nullptr, nullptr, nullptr, dump, 0);
    skel_iter<<<grd, blk, 0, stream>>>(b1, b0, pred, pA, nullptr, nullptr, nullptr, nullptr, dump, 0);
    skel_iter<<<grd, blk, 0, stream>>>(b0, b1, pred, pA, nullptr, nullptr, nullptr, nullptr, dump, 0);
    skel_iter<<<grd, blk, 0, stream>>>(b1, b0, pred, pA, nullptr, nullptr, nullptr, nullptr, dump, 1);
    skel_iter<<<grd, blk, 0, stream>>>(pred, b0, target, pB, nullptr, nullptr, nullptr, nullptr, dump, 0);
    skel_iter<<<grd, blk, 0, stream>>>(b0, b1, target, pB, nullptr, nullptr, nullptr, nullptr, dump, 0);
    skel_iter<<<grd, blk, 0, stream>>>(b1, b0, target, pB, nullptr, nullptr, nullptr, nullptr, dump, 0);
    skel_iter<<<grd, blk, 0, stream>>>(b0, b1, target, pB, nullptr, nullptr, nullptr, nullptr, dump, 0);
    skel_iter<<<grd, blk, 0, stream>>>(b1, b0, target, pB, nullptr, nullptr, nullptr, nullptr, dump, 1);
    finalize_kernel<<<1, 256, 0, stream>>>(pA, pB, out, NPART);
  }
}